// Round 7
// baseline (495.093 us; speedup 1.0000x reference)
//
#include <hip/hip_runtime.h>

typedef __bf16 bf16;
typedef __attribute__((ext_vector_type(8))) __bf16 bf16x8;
typedef __attribute__((ext_vector_type(4))) __bf16 bf16x4;
typedef __attribute__((ext_vector_type(4))) float f32x4;
typedef unsigned int u32;

#define MFMA16(a, b, c) __builtin_amdgcn_mfma_f32_16x16x32_bf16(a, b, c, 0, 0, 0)

__device__ __forceinline__ int div7(int n) { return (n * 37) >> 8; }          // exact 0..63
__device__ __forceinline__ int relv(int n) { return n + 6 * div7(n); }        // 13*(n/7)+(n%7)

#define QSCALE 0.17677669529663687f   // 32^-0.5, folded into Q

// ---------------- prep: pack weights (bf16 MFMA B-frag order) + bake logit tables ---------
// ws layout:
//   bf16x8 frags [0,2304): Wq  [t=0..11][ks=0..2][lane]  (qkv_w)
//                [2304,3456): Wsk [t=0..5][ks=0..2][lane] (skip_w * QSCALE)
//                [3456,4608): Wpr [t=0..5][h=0..2][lane]  (proj_w, permuted quad layout)
//   f32 PB at byte 73728: [vh=12][quad=4][nt=4][q=64][r=4] logit offsets
__global__ __launch_bounds__(256)
void prep(const float* __restrict__ qkv_w, const float* __restrict__ skip_w,
          const float* __restrict__ proj_w, const float* __restrict__ btab,
          bf16* __restrict__ ws)
{
    const int blk = blockIdx.x, tid = threadIdx.x;
    if (blk < 18) {
        const int j = blk * 256 + tid;
        bf16x8 v;
        if (j < 2304) {
            int t = j / 192, rem = j - t * 192;
            int ks = rem >> 6, lane = rem & 63, q = lane >> 4, l16 = lane & 15;
            const float* p = qkv_w + (16 * t + l16) * 96 + ks * 32 + q * 8;
            #pragma unroll
            for (int e = 0; e < 8; ++e) v[e] = (bf16)p[e];
        } else if (j < 3456) {
            int i = j - 2304;
            int t = i / 192, rem = i - t * 192;
            int ks = rem >> 6, lane = rem & 63, q = lane >> 4, l16 = lane & 15;
            const float* p = skip_w + (16 * t + l16) * 96 + ks * 32 + q * 8;
            #pragma unroll
            for (int e = 0; e < 8; ++e) v[e] = (bf16)(p[e] * QSCALE);
        } else {
            int i = j - 3456;
            int t = i / 192, rem = i - t * 192;
            int h = rem >> 6, lane = rem & 63, q = lane >> 4, l16 = lane & 15;
            const float* p = proj_w + (16 * t + l16) * 96 + 32 * h + 4 * q;
            #pragma unroll
            for (int r = 0; r < 4; ++r) { v[r] = (bf16)p[r]; v[4 + r] = (bf16)p[16 + r]; }
        }
        ((bf16x8*)ws)[j] = v;
    } else {
        const int idx = (blk - 18) * 256 + tid;          // 0..49151
        const int r  = idx & 3;
        const int q  = (idx >> 2) & 63;
        const int nt = (idx >> 8) & 3;
        const int qd = (idx >> 10) & 3;
        const int vh = idx >> 12;                        // variant*3 + h
        const int vr = vh / 3, h = vh - 3 * vr;
        const int ebit = vr >> 1, wbit = vr & 1;         // (wi==31), (wj==31)
        const int k = 8 * qd + 32 * (nt >> 1) + 4 * (nt & 1) + r;
        const int qc = (q < 49) ? q : 48;
        float val;
        if (k >= 49) {
            val = -20000.f;
        } else {
            val = btab[(relv(qc) + relv(48 - k)) * 3 + h];
            int rq = div7(qc), cq = qc - 7 * rq;
            int rk = div7(k),  ck = k - 7 * rk;
            int gq = (ebit ? (rq < 4 ? 3 : 6) : 0) + (wbit ? (cq < 4 ? 1 : 2) : 0);
            int gk = (ebit ? (rk < 4 ? 3 : 6) : 0) + (wbit ? (ck < 4 ? 1 : 2) : 0);
            if (gq != gk) val -= 100.f;
        }
        ((float*)(ws + 36864))[idx] = val;
    }
}

// ---------------- main: one block = FOUR 7x7 windows (pipelined), 256 threads ----------------
// (256,3): arch-VGPR cap ~84 (even arch/accum split of 512/3) -> no spills at ~80 arch.
// LDS 53760 B x 3 = 157.5 KiB -> 3 blocks/CU. Window w+1's HBM gather is issued after S1
// and lands before S2, hidden under B1+B2's 54 MFMAs (T14 issue-early/write-late).
__global__ __launch_bounds__(256, 3)
void swin_msa_kernel(const float* __restrict__ x_in,   const float* __restrict__ sx_in,
                     const bf16*  __restrict__ wpk,    const float* __restrict__ qkv_b,
                     const float* __restrict__ skip_b, const float* __restrict__ proj_b,
                     float* __restrict__ out)
{
    __shared__ __align__(16) unsigned short smem[26880];   // 53760 B
    bf16* buf0 = (bf16*)smem;        // 64x104: X stage (even w) / Kb overlay
    bf16* buf1 = buf0 + 6656;        // 64x104: X stage (odd w)  / Kb overlay
    bf16* Qb   = buf0 + 13312;       // 64x104
    bf16* VT   = buf0 + 19968;       // 96x72 (V transposed: [channel][pixel])

    const int tid  = threadIdx.x;
    const int wv   = tid >> 6;
    const int lane = tid & 63;
    const int quad = lane >> 4;
    const int l16  = lane & 15;
    const int koff = quad * 8;

    const f32x4 zero4 = {0.f, 0.f, 0.f, 0.f};

    const bf16x8* WQ = (const bf16x8*)wpk + lane;          // + (t*3+ks)*64
    const bf16x8* WS = (const bf16x8*)wpk + 2304 + lane;   // + (t*3+ks)*64
    const bf16x8* WP = (const bf16x8*)wpk + 3456 + lane;   // + (t*3+h)*64
    const f32x4*  PB4 = (const f32x4*)((const float*)(wpk + 36864));

    // per-thread gather geometry (window-invariant): 4 threads/pixel, 24 floats each
    const int gp   = tid >> 2;
    const int gseg = tid & 3;
    const int gpc  = (gp < 49) ? gp : 48;
    const int grr  = div7(gpc), gcc = gpc - 7 * grr;

    // attention/store pixel geometry
    const int pq  = 16 * wv + l16;
    const int pqc = (pq < 49) ? pq : 48;
    const int pr  = div7(pqc), pc = pqc - 7 * pr;

    // window context: gbase (asx/store), gsrc (gather), pb0 (logit table)
    auto wctx = [&](int win, int& gbase_, int& gsrc_, int& pb0_) {
        int bimg = win >> 10, wrem = win & 1023, wi = wrem >> 5, wj = wrem & 31;
        int ph = wi * 7 + pr + 3; if (ph >= 224) ph -= 224;
        int pw = wj * 7 + pc + 3; if (pw >= 224) pw -= 224;
        gbase_ = ((bimg * 224 + ph) * 224 + pw) * 96;
        int gh = wi * 7 + grr + 3; if (gh >= 224) gh -= 224;
        int gw = wj * 7 + gcc + 3; if (gw >= 224) gw -= 224;
        gsrc_ = ((bimg * 224 + gh) * 224 + gw) * 96 + gseg * 24;
        int variant = ((wi == 31) ? 2 : 0) + ((wj == 31) ? 1 : 0);
        pb0_ = ((variant * 3) * 4 + quad) * 4 * 64 + pq;
    };

    // ---- prologue: window 0 gather + sx, staged into buf0 ----
    int gbase, gsrc, pb0;
    wctx(blockIdx.x * 4, gbase, gsrc, pb0);
    bf16x8 asx[3];
    {
        const float* s = x_in + gsrc;
        f32x4 a0 = __builtin_nontemporal_load((const f32x4*)s);
        f32x4 a1 = __builtin_nontemporal_load((const f32x4*)(s + 4));
        f32x4 a2 = __builtin_nontemporal_load((const f32x4*)(s + 8));
        f32x4 a3 = __builtin_nontemporal_load((const f32x4*)(s + 12));
        f32x4 a4 = __builtin_nontemporal_load((const f32x4*)(s + 16));
        f32x4 a5 = __builtin_nontemporal_load((const f32x4*)(s + 20));
        #pragma unroll
        for (int ks = 0; ks < 3; ++ks) {
            const float* sp = sx_in + gbase + ks * 32 + koff;
            f32x4 b0 = __builtin_nontemporal_load((const f32x4*)sp);
            f32x4 b1 = __builtin_nontemporal_load((const f32x4*)(sp + 4));
            bf16x8 r;
            #pragma unroll
            for (int e = 0; e < 4; ++e) { r[e] = (bf16)b0[e]; r[4 + e] = (bf16)b1[e]; }
            asx[ks] = r;
        }
        bf16* dst = buf0 + gp * 104 + gseg * 24;
        bf16x8 w0, w1, w2;
        #pragma unroll
        for (int e = 0; e < 4; ++e) {
            w0[e] = (bf16)a0[e]; w0[4 + e] = (bf16)a1[e];
            w1[e] = (bf16)a2[e]; w1[4 + e] = (bf16)a3[e];
            w2[e] = (bf16)a4[e]; w2[4 + e] = (bf16)a5[e];
        }
        *(bf16x8*)(dst)      = w0;
        *(bf16x8*)(dst + 8)  = w1;
        *(bf16x8*)(dst + 16) = w2;
    }

    int ngbase = gbase, ngsrc = gsrc, npb0 = pb0;

    #pragma unroll 1
    for (int w = 0; w < 4; ++w) {
        bf16* Xc = (w & 1) ? buf1 : buf0;     // current: staged X, later Kb overlay
        bf16* Xn = (w & 1) ? buf0 : buf1;     // next: free (its Kb was read by C(w-1))
        __syncthreads();                      // S1: X_w staged; C(w-1) fully done

        const bool more = (w < 3);
        // issue next window's X gather immediately (hidden under B1+B2)
        f32x4 ga0, ga1, ga2, ga3, ga4, ga5;
        if (more) {
            wctx(blockIdx.x * 4 + w + 1, ngbase, ngsrc, npb0);
            const float* s = x_in + ngsrc;
            ga0 = __builtin_nontemporal_load((const f32x4*)s);
            ga1 = __builtin_nontemporal_load((const f32x4*)(s + 4));
            ga2 = __builtin_nontemporal_load((const f32x4*)(s + 8));
            ga3 = __builtin_nontemporal_load((const f32x4*)(s + 12));
            ga4 = __builtin_nontemporal_load((const f32x4*)(s + 16));
            ga5 = __builtin_nontemporal_load((const f32x4*)(s + 20));
        }

        // ---- B1 (N-split): KV = X @ qkv_w^T; wave wv owns t = 3wv..3wv+2 ----
        f32x4 acc[4][3];
        #pragma unroll
        for (int m = 0; m < 4; ++m)
            #pragma unroll
            for (int j = 0; j < 3; ++j) acc[m][j] = zero4;
        const int tb = 3 * wv;
        #pragma unroll
        for (int ks = 0; ks < 3; ++ks) {
            bf16x8 a[4];
            #pragma unroll
            for (int m = 0; m < 4; ++m)
                a[m] = *(const bf16x8*)(Xc + (16 * m + l16) * 104 + ks * 32 + koff);
            #pragma unroll
            for (int j = 0; j < 3; ++j) {
                bf16x8 b = WQ[((tb + j) * 3 + ks) * 64];
                #pragma unroll
                for (int m = 0; m < 4; ++m) acc[m][j] = MFMA16(a[m], b, acc[m][j]);
            }
        }
        // ---- B2 (M-split): Q = SX @ (skip_w*scale)^T ----
        f32x4 qa[6];
        #pragma unroll
        for (int t = 0; t < 6; ++t) qa[t] = zero4;
        #pragma unroll
        for (int ks = 0; ks < 3; ++ks)
            #pragma unroll
            for (int t = 0; t < 6; ++t)
                qa[t] = MFMA16(asx[ks], WS[(t * 3 + ks) * 64], qa[t]);

        // asx dead: issue next window's sx loads (converted after C)
        f32x4 sraw[6];
        if (more) {
            #pragma unroll
            for (int ks = 0; ks < 3; ++ks) {
                const float* sp = sx_in + ngbase + ks * 32 + koff;
                sraw[2 * ks]     = __builtin_nontemporal_load((const f32x4*)sp);
                sraw[2 * ks + 1] = __builtin_nontemporal_load((const f32x4*)(sp + 4));
            }
        }

        // write Qb (region free since C(w-1) finished before S1)
        {
            const int row = 16 * wv + 4 * quad;
            #pragma unroll
            for (int t = 0; t < 6; ++t) {
                const float bias = skip_b[16 * t + l16] * QSCALE;
                #pragma unroll
                for (int r = 0; r < 4; ++r)
                    Qb[(row + r) * 104 + 16 * t + l16] = (bf16)(qa[t][r] + bias);
            }
        }
        // stage X_{w+1} -> Xn (Xn's old Kb was read by C(w-1), done before S1)
        if (more) {
            bf16* dst = Xn + gp * 104 + gseg * 24;
            bf16x8 w0, w1, w2;
            #pragma unroll
            for (int e = 0; e < 4; ++e) {
                w0[e] = (bf16)ga0[e]; w0[4 + e] = (bf16)ga1[e];
                w1[e] = (bf16)ga2[e]; w1[4 + e] = (bf16)ga3[e];
                w2[e] = (bf16)ga4[e]; w2[4 + e] = (bf16)ga5[e];
            }
            *(bf16x8*)(dst)      = w0;
            *(bf16x8*)(dst + 8)  = w1;
            *(bf16x8*)(dst + 16) = w2;
        }
        __syncthreads();                      // S2: Xc reads done; X_{w+1} staged

        // ---- K/V epilogue: Kb overlays Xc (rho rows); VT separate ----
        if (wv < 2) {
            #pragma unroll
            for (int j = 0; j < 3; ++j) {
                const int col = 16 * (tb + j) + l16;
                const float bias = qkv_b[col];
                #pragma unroll
                for (int m = 0; m < 4; ++m) {
                    const int rho = 32 * (m >> 1) + 16 * (quad & 1) + 8 * (m & 1) + 4 * (quad >> 1);
                    #pragma unroll
                    for (int r = 0; r < 4; ++r)
                        Xc[(rho + r) * 104 + col] = (bf16)(acc[m][j][r] + bias);
                }
            }
        } else {
            #pragma unroll
            for (int j = 0; j < 3; ++j) {
                const int ch = 16 * (tb + j - 6) + l16;
                const float bias = qkv_b[16 * (tb + j) + l16];
                #pragma unroll
                for (int m = 0; m < 4; ++m) {
                    bf16x4 vv;
                    #pragma unroll
                    for (int r = 0; r < 4; ++r) vv[r] = (bf16)(acc[m][j][r] + bias);
                    *(bf16x4*)(VT + ch * 72 + 16 * m + 4 * quad) = vv;
                }
            }
        }
        // preload head-0 logit offsets (off the serial chain)
        f32x4 pbv[4];
        #pragma unroll
        for (int nt = 0; nt < 4; ++nt) pbv[nt] = PB4[pb0 + nt * 64];

        __syncthreads();                      // S3: Kb/Qb/VT visible

        // ---- C: attention + proj, registers only ----
        f32x4 dacc[6];
        #pragma unroll
        for (int t = 0; t < 6; ++t) dacc[t] = zero4;

        #pragma unroll
        for (int h = 0; h < 3; ++h) {
            const bf16x8 bq = *(const bf16x8*)(Qb + (16 * wv + l16) * 104 + 32 * h + koff);
            f32x4 s[4];
            #pragma unroll
            for (int nt = 0; nt < 4; ++nt) {
                bf16x8 ak = *(const bf16x8*)(Xc + (16 * nt + l16) * 104 + 32 * h + koff);
                f32x4 cin = (h == 0) ? pbv[nt] : PB4[pb0 + h * 1024 + nt * 64];
                s[nt] = MFMA16(ak, bq, cin);
            }
            float v[16];
            #pragma unroll
            for (int nt = 0; nt < 4; ++nt)
                #pragma unroll
                for (int r = 0; r < 4; ++r) v[nt * 4 + r] = __expf(s[nt][r]);
            float s01 = (v[0] + v[1]) + (v[2] + v[3]);
            float s23 = (v[4] + v[5]) + (v[6] + v[7]);
            float s45 = (v[8] + v[9]) + (v[10] + v[11]);
            float s67 = (v[12] + v[13]) + (v[14] + v[15]);
            float sm = (s01 + s23) + (s45 + s67);
            sm += __shfl_xor(sm, 16);
            sm += __shfl_xor(sm, 32);
            const float isv = 1.0f / sm;

            bf16x8 bp0, bp1;
            #pragma unroll
            for (int j = 0; j < 8; ++j) { bp0[j] = (bf16)v[j]; bp1[j] = (bf16)v[8 + j]; }
            const bf16* vb = VT + (32 * h + l16) * 72 + koff;
            f32x4 o0 = zero4, o1 = zero4;
            o0 = MFMA16(*(const bf16x8*)(vb),                bp0, o0);
            o0 = MFMA16(*(const bf16x8*)(vb + 32),           bp1, o0);
            o1 = MFMA16(*(const bf16x8*)(vb + 16 * 72),      bp0, o1);
            o1 = MFMA16(*(const bf16x8*)(vb + 16 * 72 + 32), bp1, o1);

            bf16x8 bo;
            #pragma unroll
            for (int r = 0; r < 4; ++r) { bo[r] = (bf16)(o0[r] * isv); bo[4 + r] = (bf16)(o1[r] * isv); }
            #pragma unroll
            for (int t = 0; t < 6; ++t)
                dacc[t] = MFMA16(WP[(t * 3 + h) * 64], bo, dacc[t]);
        }

        // ---- store window w (NT: write-once) ----
        if (pq < 49) {
            #pragma unroll
            for (int t = 0; t < 6; ++t) {
                const f32x4 pb = *(const f32x4*)(proj_b + 16 * t + 4 * quad);
                f32x4 ov;
                #pragma unroll
                for (int r = 0; r < 4; ++r) ov[r] = dacc[t][r] + pb[r];
                __builtin_nontemporal_store(ov, (f32x4*)(out + gbase + 16 * t + 4 * quad));
            }
        }

        // rotate context: convert next sx (loads issued long ago)
        if (more) {
            #pragma unroll
            for (int ks = 0; ks < 3; ++ks) {
                bf16x8 r;
                #pragma unroll
                for (int e = 0; e < 4; ++e) {
                    r[e]     = (bf16)sraw[2 * ks][e];
                    r[4 + e] = (bf16)sraw[2 * ks + 1][e];
                }
                asx[ks] = r;
            }
            gbase = ngbase;
            pb0   = npb0;
        }
    }
}

extern "C" void kernel_launch(void* const* d_in, const int* in_sizes, int n_in,
                              void* d_out, int out_size, void* d_ws, size_t ws_size,
                              hipStream_t stream) {
    (void)in_sizes; (void)n_in; (void)out_size; (void)ws_size;
    prep<<<dim3(210), dim3(256), 0, stream>>>(
        (const float*)d_in[2], (const float*)d_in[4], (const float*)d_in[6],
        (const float*)d_in[8], (bf16*)d_ws);
    swin_msa_kernel<<<dim3(1024), dim3(256), 0, stream>>>(
        (const float*)d_in[0], (const float*)d_in[1], (const bf16*)d_ws,
        (const float*)d_in[3], (const float*)d_in[5], (const float*)d_in[7],
        (float*)d_out);
}